// Round 1
// 2142.088 us; speedup vs baseline: 1.5450x; 1.5450x over previous
//
#include <hip/hip_runtime.h>

#define N_NODES   100000
#define N_EDGES   1000000
#define N_PAIRS   2000000
#define IN_CH     64
#define OUT_CH    64
#define NODE_DIM  37
#define STATE_DIM 5
#define FEAT_DIM  106   // IN_CH + NODE_DIM + STATE_DIM

__device__ __forceinline__ float elu_f(float s) {
    return s > 0.f ? s : expm1f(s);
}

// ---------------------------------------------------------------------------
// Stage 1: out[e][c] = elu(W_e[c] . edge_attr[e] + b_e[c])
// Runs FIRST. pair_kernel then atomicAdds the segment sums directly into out,
// which removes the 256MB workspace, its memset, and a full 256MB acc re-read.
// Lane c owns channel c; We row held in registers (64 VGPR) — the
// __launch_bounds__ min-waves arg caps occupancy at 4 waves/EU (128 VGPR cap)
// so the compiler CAN keep it resident (previous kernel: VGPR_Count=68 proved
// the W rows were being re-fetched every iteration as 64-lane L1 scatters).
// Two edges per wave-iteration for memory-level parallelism.
// ---------------------------------------------------------------------------
__global__ __launch_bounds__(256, 4) void base_kernel(
    const float* __restrict__ ea,    // [N_EDGES, 64]
    const float* __restrict__ We,    // [64, 64]
    const float* __restrict__ be,    // [64]
    float* __restrict__ out)         // [N_EDGES, 64]
{
    const int t    = threadIdx.x;
    const int wave = __builtin_amdgcn_readfirstlane(t >> 6);
    const int lane = t & 63;

    float wrow[IN_CH];
    #pragma unroll
    for (int j = 0; j < IN_CH; ++j)
        wrow[j] = We[lane * IN_CH + j];
    const float bias = be[lane];

    const int gw  = blockIdx.x * 4 + wave;   // global wave id (uniform)
    const int gws = gridDim.x * 4;
    for (int e = gw * 2; e < N_EDGES; e += gws * 2) {  // N_EDGES even
        const float4* r0 = (const float4*)(ea + (size_t)e * IN_CH);
        const float4* r1 = (const float4*)(ea + (size_t)(e + 1) * IN_CH);
        float a0 = bias, a1 = 0.f, a2 = 0.f, a3 = 0.f;
        float b0 = bias, b1 = 0.f, b2 = 0.f, b3 = 0.f;
        #pragma unroll
        for (int q = 0; q < IN_CH / 4; ++q) {
            const float4 f = r0[q];
            const float4 g = r1[q];
            a0 = fmaf(wrow[4 * q + 0], f.x, a0);
            a1 = fmaf(wrow[4 * q + 1], f.y, a1);
            a2 = fmaf(wrow[4 * q + 2], f.z, a2);
            a3 = fmaf(wrow[4 * q + 3], f.w, a3);
            b0 = fmaf(wrow[4 * q + 0], g.x, b0);
            b1 = fmaf(wrow[4 * q + 1], g.y, b1);
            b2 = fmaf(wrow[4 * q + 2], g.z, b2);
            b3 = fmaf(wrow[4 * q + 3], g.w, b3);
        }
        out[(size_t)e * OUT_CH + lane]       = elu_f((a0 + a1) + (a2 + a3));
        out[(size_t)(e + 1) * OUT_CH + lane] = elu_f((b0 + b1) + (b2 + b3));
    }
}

// ---------------------------------------------------------------------------
// Stage 2: one WAVE per pair, TWO pairs per iteration. Lane c owns channel c
// and holds W_edge[c][:] (106 fp32) in registers. min-waves=2 caps the VGPR
// budget at 256 so wrow[106] is guaranteed register-resident (the old kernel's
// 68-VGPR allocation forced per-FMA W reloads — the measured bottleneck).
// All six index loads for the two pairs are issued up front; the two dot
// products interleave, doubling outstanding uniform feat loads.
//   h = elu(W.feat + b);  atomicAdd(out[seg][c], h)
// ---------------------------------------------------------------------------
__global__ __launch_bounds__(256, 2) void pair_kernel(
    const float* __restrict__ x,     // [N_NODES, 37]
    const float* __restrict__ gs,    // [N_NODES, 5]
    const float* __restrict__ ea,    // [N_EDGES, 64]
    const float* __restrict__ W,     // [64, 106]
    const float* __restrict__ b,     // [64]
    const int* __restrict__ aidx,    // [2, N_PAIRS]
    const int* __restrict__ eidx,    // [2, N_PAIRS]
    float* __restrict__ out)         // [N_EDGES, 64] — accumulated in place
{
    const int t    = threadIdx.x;
    const int wave = __builtin_amdgcn_readfirstlane(t >> 6);
    const int lane = t & 63;

    float wrow[FEAT_DIM];
    #pragma unroll
    for (int j = 0; j < FEAT_DIM; ++j)
        wrow[j] = W[lane * FEAT_DIM + j];
    const float bias = b[lane];

    const int gw  = blockIdx.x * 4 + wave;   // global wave id (uniform)
    const int gws = gridDim.x * 4;
    for (int k = gw * 2; k < N_PAIRS; k += gws * 2) {  // N_PAIRS even
        // --- all index loads up front (adjacent pairs merge to dwordx2) ---
        const int segA = eidx[k];                    // e_idx[0][k]
        const int segB = eidx[k + 1];
        const int e2A  = eidx[N_PAIRS + k];          // e_idx[1][k]
        const int e2B  = eidx[N_PAIRS + k + 1];
        const int a0A  = aidx[k];                    // atom_index[0][k]
        const int a0B  = aidx[k + 1];

        const float4* rA = (const float4*)(ea + (size_t)e2A * IN_CH);
        const float4* rB = (const float4*)(ea + (size_t)e2B * IN_CH);
        const float*  xA = x  + (size_t)a0A * NODE_DIM;
        const float*  xB = x  + (size_t)a0B * NODE_DIM;
        const float*  gA = gs + (size_t)a0A * STATE_DIM;
        const float*  gB = gs + (size_t)a0B * STATE_DIM;

        float sA0 = bias, sA1 = 0.f, sA2 = 0.f, sA3 = 0.f;
        float sB0 = bias, sB1 = 0.f, sB2 = 0.f, sB3 = 0.f;

        #pragma unroll
        for (int q = 0; q < IN_CH / 4; ++q) {        // 2 x 16 uniform float4
            const float4 f = rA[q];
            const float4 g = rB[q];
            sA0 = fmaf(wrow[4 * q + 0], f.x, sA0);
            sA1 = fmaf(wrow[4 * q + 1], f.y, sA1);
            sA2 = fmaf(wrow[4 * q + 2], f.z, sA2);
            sA3 = fmaf(wrow[4 * q + 3], f.w, sA3);
            sB0 = fmaf(wrow[4 * q + 0], g.x, sB0);
            sB1 = fmaf(wrow[4 * q + 1], g.y, sB1);
            sB2 = fmaf(wrow[4 * q + 2], g.z, sB2);
            sB3 = fmaf(wrow[4 * q + 3], g.w, sB3);
        }
        #pragma unroll
        for (int j = 0; j < 36; j += 4) {            // node features, 4 chains
            sA0 = fmaf(wrow[IN_CH + j + 0], xA[j + 0], sA0);
            sA1 = fmaf(wrow[IN_CH + j + 1], xA[j + 1], sA1);
            sA2 = fmaf(wrow[IN_CH + j + 2], xA[j + 2], sA2);
            sA3 = fmaf(wrow[IN_CH + j + 3], xA[j + 3], sA3);
            sB0 = fmaf(wrow[IN_CH + j + 0], xB[j + 0], sB0);
            sB1 = fmaf(wrow[IN_CH + j + 1], xB[j + 1], sB1);
            sB2 = fmaf(wrow[IN_CH + j + 2], xB[j + 2], sB2);
            sB3 = fmaf(wrow[IN_CH + j + 3], xB[j + 3], sB3);
        }
        sA0 = fmaf(wrow[IN_CH + 36], xA[36], sA0);   // node tail (j=36)
        sB0 = fmaf(wrow[IN_CH + 36], xB[36], sB0);
        #pragma unroll
        for (int j = 0; j < STATE_DIM; ++j) {        // global state (5)
            sA1 = fmaf(wrow[IN_CH + NODE_DIM + j], gA[j], sA1);
            sB1 = fmaf(wrow[IN_CH + NODE_DIM + j], gB[j], sB1);
        }

        const float hA = elu_f((sA0 + sA1) + (sA2 + sA3));
        const float hB = elu_f((sB0 + sB1) + (sB2 + sB3));
        atomicAdd(&out[(size_t)segA * OUT_CH + lane], hA);
        atomicAdd(&out[(size_t)segB * OUT_CH + lane], hB);
    }
}

extern "C" void kernel_launch(void* const* d_in, const int* in_sizes, int n_in,
                              void* d_out, int out_size, void* d_ws, size_t ws_size,
                              hipStream_t stream) {
    const float* x    = (const float*)d_in[0];
    const float* gs   = (const float*)d_in[1];
    const float* ea   = (const float*)d_in[2];
    const float* W    = (const float*)d_in[3];
    const float* b    = (const float*)d_in[4];
    const float* We   = (const float*)d_in[5];
    const float* be   = (const float*)d_in[6];
    const int*   aidx = (const int*)d_in[7];
    const int*   eidx = (const int*)d_in[8];
    float* out = (float*)d_out;

    // Stage 1 writes the elu(ea@We^T + be) term; stage 2 accumulates the
    // segment sums on top with device-scope fp32 atomics (same stream order
    // guarantees stage 1 completes first). No workspace needed.
    base_kernel<<<2048, 256, 0, stream>>>(ea, We, be, out);
    pair_kernel<<<2048, 256, 0, stream>>>(x, gs, ea, W, b, aidx, eidx, out);
}